// Round 7
// baseline (392.242 us; speedup 1.0000x reference)
//
#include <hip/hip_runtime.h>
#include <stdint.h>

#define Bn 16384
#define Dn 64
#define Hn 256

typedef short bf16x8 __attribute__((ext_vector_type(8)));
typedef float f32x4 __attribute__((ext_vector_type(4)));

// ---------- x transpose: xT[d][row] (tiled, conflict-free) ----------
__global__ __launch_bounds__(256) void xpose(const float* __restrict__ x,
                                             float* __restrict__ xT) {
  __shared__ float tile[64][65];
  int t = threadIdx.x;
  int r0 = blockIdx.x * 64;
  int c = t & 63, rr = t >> 6;
  #pragma unroll
  for (int i = 0; i < 16; ++i)
    tile[rr + i * 4][c] = x[(size_t)(r0 + rr + i * 4) * Dn + c];
  __syncthreads();
  #pragma unroll
  for (int i = 0; i < 16; ++i)
    xT[(size_t)(rr + i * 4) * Bn + r0 + c] = tile[c][rr + i * 4];
}

// ---------- transpose small tail weights for coalesced reads ----------
__global__ __launch_bounds__(256) void prep_t(
    const float* __restrict__ Wq, const float* __restrict__ Wk,
    const float* __restrict__ Wc1, const float* __restrict__ Ws,
    float* __restrict__ WqT, float* __restrict__ WkT,
    float* __restrict__ Wc1T, float* __restrict__ WsT) {
  int t = blockIdx.x * 256 + threadIdx.x;   // 16384
  int h = t >> 6, dd = t & 63;
  WqT[dd * 256 + h]  = Wq[h * 64 + dd];
  WkT[dd * 256 + h]  = Wk[h * 64 + dd];
  Wc1T[dd * 256 + h] = Wc1[h * 64 + dd];
  WsT[h * 64 + dd]   = Ws[dd * 256 + h];
}

// ---------- persistent fused GEMM, column-split ----------
// 2048 blocks = 8 xcd x 8 dlocal x 2 col-half x 16 chunks; 256 threads =
// 4 waves 1M x 4N, wave tile 32 rows x 32 cols, BM=32, block cols = 128.
// breg = 16 frags (64 VGPR) gathered once; a1 streamed via 2x16KB LDS dbuf
// (wave w computes k-range [64w,64w+64) of next tile inside current tile's
// K-loop); W1/b1/b2/W3 slices re-read from L1 to stay under the 128-reg /
// 4-waves-per-SIMD cliff. Each half writes partial h to hcP[half]; tail sums.
__global__ __launch_bounds__(256, 4) void gemm_hcat(
    const float* __restrict__ xT, const float* __restrict__ W1,
    const float* __restrict__ b1, const float* __restrict__ W2,
    const float* __restrict__ b2, const float* __restrict__ W3,
    float* __restrict__ hcP) {
  __shared__ char As[2][16384];   // [slot(16)=stage*2+gm][lane(64)][16B]
  __shared__ float P[2][4][32];

  int bid = blockIdx.x;
  int xcd = bid & 7;
  int rest = bid >> 3;
  int dl = rest & 7;
  int half = (rest >> 3) & 1;
  int chunk = rest >> 4;             // 0..15
  int d = xcd * 8 + dl;              // 8 d per XCD -> W2 slices L2-resident
  int base = chunk * 1024;

  int tid = threadIdx.x;
  int lane = tid & 63;
  int w = tid >> 6;                  // wave id = wn; also owns k-range 64w..64w+63
  int l15 = lane & 15;
  int g = lane >> 4;
  int colbase = half * 128 + w * 32;

  const float* W2d = W2 + (size_t)d * Hn * Hn;
  const float* xTd = xT + (size_t)d * Bn + base;
  const float* W1d = W1 + d * Hn;
  const float* b1d = b1 + d * Hn;
  const float* b2d = b2 + d * Hn;
  const float* W3d = W3 + d * Hn;

  // one-time gather: B fragments straight from W2 (fp32) -> bf16 regs
  bf16x8 breg[16];
  #pragma unroll
  for (int s = 0; s < 8; ++s)
    #pragma unroll
    for (int nj = 0; nj < 2; ++nj) {
      const float* src = W2d + (size_t)(s * 32 + g * 8) * Hn + colbase + nj * 16 + l15;
      float u0 = src[0],      u1 = src[Hn],     u2 = src[2 * Hn], u3 = src[3 * Hn];
      float u4 = src[4 * Hn], u5 = src[5 * Hn], u6 = src[6 * Hn], u7 = src[7 * Hn];
      union { uint4 u; bf16x8 v; } pk;
      asm("v_cvt_pk_bf16_f32 %0, %1, %2" : "=v"(pk.u.x) : "v"(u0), "v"(u1));
      asm("v_cvt_pk_bf16_f32 %0, %1, %2" : "=v"(pk.u.y) : "v"(u2), "v"(u3));
      asm("v_cvt_pk_bf16_f32 %0, %1, %2" : "=v"(pk.u.z) : "v"(u4), "v"(u5));
      asm("v_cvt_pk_bf16_f32 %0, %1, %2" : "=v"(pk.u.w) : "v"(u6), "v"(u7));
      breg[s * 2 + nj] = pk.v;
    }

  // a1 chunk c (0..3): stage = 2w + (c&1), row-group gm = c>>1.
  // thread computes 8 values at k = stage*32 + g*8 + j for row gm*16+l15.
  #define A1CHUNK(wbuf, c, xv)                                                  \
    {                                                                           \
      int st = 2 * w + ((c) & 1);                                               \
      int k0 = st * 32 + g * 8;                                                 \
      float4 wa = *(const float4*)(W1d + k0);                                   \
      float4 wbq = *(const float4*)(W1d + k0 + 4);                              \
      float4 ba = *(const float4*)(b1d + k0);                                   \
      float4 bbq = *(const float4*)(b1d + k0 + 4);                              \
      float v0 = fmaxf(fmaf((xv), wa.x, ba.x), 0.f);                            \
      float v1 = fmaxf(fmaf((xv), wa.y, ba.y), 0.f);                            \
      float v2 = fmaxf(fmaf((xv), wa.z, ba.z), 0.f);                            \
      float v3 = fmaxf(fmaf((xv), wa.w, ba.w), 0.f);                            \
      float v4 = fmaxf(fmaf((xv), wbq.x, bbq.x), 0.f);                          \
      float v5 = fmaxf(fmaf((xv), wbq.y, bbq.y), 0.f);                          \
      float v6 = fmaxf(fmaf((xv), wbq.z, bbq.z), 0.f);                          \
      float v7 = fmaxf(fmaf((xv), wbq.w, bbq.w), 0.f);                          \
      uint4 pk;                                                                 \
      asm("v_cvt_pk_bf16_f32 %0, %1, %2" : "=v"(pk.x) : "v"(v0), "v"(v1));      \
      asm("v_cvt_pk_bf16_f32 %0, %1, %2" : "=v"(pk.y) : "v"(v2), "v"(v3));      \
      asm("v_cvt_pk_bf16_f32 %0, %1, %2" : "=v"(pk.z) : "v"(v4), "v"(v5));      \
      asm("v_cvt_pk_bf16_f32 %0, %1, %2" : "=v"(pk.w) : "v"(v6), "v"(v7));      \
      *(uint4*)((wbuf) + (st * 2 + ((c) >> 1)) * 1024 + lane * 16) = pk;        \
    }

  // prologue: a1 for tile 0
  {
    float x0 = xTd[l15];
    float x1 = xTd[16 + l15];
    A1CHUNK(As[0], 0, x0);
    A1CHUNK(As[0], 1, x0);
    A1CHUNK(As[0], 2, x1);
    A1CHUNK(As[0], 3, x1);
  }
  __syncthreads();

  float* hcPd = hcP + ((size_t)half * Dn + d) * Bn + base;

  for (int t = 0; t < 32; ++t) {
    int p = t & 1;
    const char* rb = As[p];
    char* wb = As[p ^ 1];
    bool pre = (t < 31);
    float xn[2];
    if (pre) {
      xn[0] = xTd[(t + 1) * 32 + l15];
      xn[1] = xTd[(t + 1) * 32 + 16 + l15];
    }

    // acc init = b2 (folded)
    f32x4 acc[2][2];
    {
      float4 bv0 = *(const float4*)(b2d + colbase + g * 4);
      float4 bv1 = *(const float4*)(b2d + colbase + 16 + g * 4);
      f32x4 i0 = {bv0.x, bv0.y, bv0.z, bv0.w};
      f32x4 i1 = {bv1.x, bv1.y, bv1.z, bv1.w};
      acc[0][0] = i0; acc[1][0] = i0;
      acc[0][1] = i1; acc[1][1] = i1;
    }

    #pragma unroll
    for (int s = 0; s < 8; ++s) {
      bf16x8 af0 = *(const bf16x8*)(rb + (s * 2 + 0) * 1024 + lane * 16);
      bf16x8 af1 = *(const bf16x8*)(rb + (s * 2 + 1) * 1024 + lane * 16);
      if (pre && s < 4) { A1CHUNK(wb, s, xn[s >> 1]); }   // next tile's a1
      __builtin_amdgcn_s_setprio(1);
      acc[0][0] = __builtin_amdgcn_mfma_f32_16x16x32_bf16(breg[s * 2 + 0], af0, acc[0][0], 0, 0, 0);
      acc[1][0] = __builtin_amdgcn_mfma_f32_16x16x32_bf16(breg[s * 2 + 0], af1, acc[1][0], 0, 0, 0);
      acc[0][1] = __builtin_amdgcn_mfma_f32_16x16x32_bf16(breg[s * 2 + 1], af0, acc[0][1], 0, 0, 0);
      acc[1][1] = __builtin_amdgcn_mfma_f32_16x16x32_bf16(breg[s * 2 + 1], af1, acc[1][1], 0, 0, 0);
      __builtin_amdgcn_s_setprio(0);
    }

    // epilogue: relu . W3 over this wave's 32 cols (rows in l15, cols in g/nj/i)
    {
      float4 wv0 = *(const float4*)(W3d + colbase + g * 4);
      float4 wv1 = *(const float4*)(W3d + colbase + 16 + g * 4);
      float* Pb = (float*)P[p];
      #pragma unroll
      for (int mi = 0; mi < 2; ++mi) {
        float ph;
        ph = fmaxf(acc[mi][0][0], 0.f) * wv0.x;
        ph = fmaf(fmaxf(acc[mi][0][1], 0.f), wv0.y, ph);
        ph = fmaf(fmaxf(acc[mi][0][2], 0.f), wv0.z, ph);
        ph = fmaf(fmaxf(acc[mi][0][3], 0.f), wv0.w, ph);
        ph = fmaf(fmaxf(acc[mi][1][0], 0.f), wv1.x, ph);
        ph = fmaf(fmaxf(acc[mi][1][1], 0.f), wv1.y, ph);
        ph = fmaf(fmaxf(acc[mi][1][2], 0.f), wv1.z, ph);
        ph = fmaf(fmaxf(acc[mi][1][3], 0.f), wv1.w, ph);
        ph += __shfl_xor(ph, 16);
        ph += __shfl_xor(ph, 32);
        if (lane < 16) Pb[w * 32 + mi * 16 + l15] = ph;
      }
    }
    __syncthreads();
    if (tid < 32) {
      float* Pb = (float*)P[p];
      hcPd[t * 32 + tid] = Pb[tid] + Pb[32 + tid] + Pb[64 + tid] + Pb[96 + tid];
    }
  }
  #undef A1CHUNK
}

// ---------- tail: attention fusion + cross MLP + g_func; 4 rows per wave ----------
__global__ __launch_bounds__(256) void fused_tail(
    const float* __restrict__ hcP, const float* __restrict__ b3,
    const float* __restrict__ WqT, const float* __restrict__ bq,
    const float* __restrict__ WkT, const float* __restrict__ bk,
    const float* __restrict__ WsT, const float* __restrict__ bs,
    const float* __restrict__ Wc1T, const float* __restrict__ bc1,
    const float* __restrict__ Wc2, const float* __restrict__ bc2,
    const float* __restrict__ Wg1, const float* __restrict__ bg1,
    const float* __restrict__ Wg2, const float* __restrict__ bg2,
    float* __restrict__ out) {
  __shared__ float hcs[4][4][64];
  __shared__ float ts[4][4][256];
  int wid = threadIdx.x >> 6;
  int lane = threadIdx.x & 63;
  int r0 = (blockIdx.x * 4 + wid) * 4;                 // 4 rows per wave
  float4 p0 = *(const float4*)(hcP + (size_t)lane * Bn + r0);
  float4 p1 = *(const float4*)(hcP + ((size_t)Dn + lane) * Bn + r0);
  float b3v = b3[lane];
  float4 hc4 = make_float4(p0.x + p1.x + b3v, p0.y + p1.y + b3v,
                           p0.z + p1.z + b3v, p0.w + p1.w + b3v);
  hcs[wid][0][lane] = hc4.x;
  hcs[wid][1][lane] = hc4.y;
  hcs[wid][2][lane] = hc4.z;
  hcs[wid][3][lane] = hc4.w;
  __syncthreads();

  float qv[4][4], kv[4][4], cv[4][4];
  #pragma unroll
  for (int j = 0; j < 4; ++j) {
    int h = lane + 64 * j;
    float bqv = bq[h], bkv = bk[h], bcv = bc1[h];
    #pragma unroll
    for (int r = 0; r < 4; ++r) { qv[r][j] = bqv; kv[r][j] = bkv; cv[r][j] = bcv; }
  }
  for (int d2 = 0; d2 < 64; ++d2) {
    float hv0 = hcs[wid][0][d2], hv1 = hcs[wid][1][d2];
    float hv2 = hcs[wid][2][d2], hv3 = hcs[wid][3][d2];
    #pragma unroll
    for (int j = 0; j < 4; ++j) {
      int h = lane + 64 * j;
      float wq = WqT[d2 * 256 + h], wk = WkT[d2 * 256 + h], wc = Wc1T[d2 * 256 + h];
      qv[0][j] = fmaf(wq, hv0, qv[0][j]); qv[1][j] = fmaf(wq, hv1, qv[1][j]);
      qv[2][j] = fmaf(wq, hv2, qv[2][j]); qv[3][j] = fmaf(wq, hv3, qv[3][j]);
      kv[0][j] = fmaf(wk, hv0, kv[0][j]); kv[1][j] = fmaf(wk, hv1, kv[1][j]);
      kv[2][j] = fmaf(wk, hv2, kv[2][j]); kv[3][j] = fmaf(wk, hv3, kv[3][j]);
      cv[0][j] = fmaf(wc, hv0, cv[0][j]); cv[1][j] = fmaf(wc, hv1, cv[1][j]);
      cv[2][j] = fmaf(wc, hv2, cv[2][j]); cv[3][j] = fmaf(wc, hv3, cv[3][j]);
    }
  }
  #pragma unroll
  for (int r = 0; r < 4; ++r)
    #pragma unroll
    for (int j = 0; j < 4; ++j)
      ts[wid][r][lane + 64 * j] = tanhf(qv[r][j] * kv[r][j]);
  __syncthreads();

  float sc[4];
  { float b = bs[lane]; sc[0] = b; sc[1] = b; sc[2] = b; sc[3] = b; }
  for (int h2 = 0; h2 < 256; ++h2) {
    float w = WsT[h2 * 64 + lane];
    sc[0] = fmaf(w, ts[wid][0][h2], sc[0]);
    sc[1] = fmaf(w, ts[wid][1][h2], sc[1]);
    sc[2] = fmaf(w, ts[wid][2][h2], sc[2]);
    sc[3] = fmaf(w, ts[wid][3][h2], sc[3]);
  }

  float hcr[4] = {hc4.x, hc4.y, hc4.z, hc4.w};
  float res[4];
  #pragma unroll
  for (int r = 0; r < 4; ++r) {
    float s = sc[r];
    float mx = s;
    #pragma unroll
    for (int off = 1; off < 64; off <<= 1) mx = fmaxf(mx, __shfl_xor(mx, off));
    float e = __expf(s - mx);
    float se = e;
    #pragma unroll
    for (int off = 1; off < 64; off <<= 1) se += __shfl_xor(se, off);
    float wgt = hcr[r] * (e / se);
    #pragma unroll
    for (int off = 1; off < 64; off <<= 1) wgt += __shfl_xor(wgt, off);
    float cp = 0.f;
    #pragma unroll
    for (int j = 0; j < 4; ++j) cp = fmaf(fmaxf(cv[r][j], 0.f), Wc2[lane + 64 * j], cp);
    #pragma unroll
    for (int off = 1; off < 64; off <<= 1) cp += __shfl_xor(cp, off);
    float comb = wgt + cp + bc2[0];
    float fp = 0.f;
    #pragma unroll
    for (int j = 0; j < 4; ++j) {
      int h = lane + 64 * j;
      fp = fmaf(fmaxf(fmaf(comb, Wg1[h], bg1[h]), 0.f), Wg2[h], fp);
    }
    #pragma unroll
    for (int off = 1; off < 64; off <<= 1) fp += __shfl_xor(fp, off);
    res[r] = fp + bg2[0];
  }
  if (lane == 0) {
    float4 o = make_float4(res[0], res[1], res[2], res[3]);
    *(float4*)(out + r0) = o;
  }
}

extern "C" void kernel_launch(void* const* d_in, const int* in_sizes, int n_in,
                              void* d_out, int out_size, void* d_ws, size_t ws_size,
                              hipStream_t stream) {
  const float* x   = (const float*)d_in[0];
  const float* W1  = (const float*)d_in[1];
  const float* b1  = (const float*)d_in[2];
  const float* W2  = (const float*)d_in[3];
  const float* b2  = (const float*)d_in[4];
  const float* W3  = (const float*)d_in[5];
  const float* b3  = (const float*)d_in[6];
  const float* Wq  = (const float*)d_in[7];
  const float* bq  = (const float*)d_in[8];
  const float* Wk  = (const float*)d_in[9];
  const float* bk  = (const float*)d_in[10];
  const float* Ws  = (const float*)d_in[11];
  const float* bs  = (const float*)d_in[12];
  const float* Wc1 = (const float*)d_in[13];
  const float* bc1 = (const float*)d_in[14];
  const float* Wc2 = (const float*)d_in[15];
  const float* bc2 = (const float*)d_in[16];
  const float* Wg1 = (const float*)d_in[17];
  const float* bg1 = (const float*)d_in[18];
  const float* Wg2 = (const float*)d_in[19];
  const float* bg2 = (const float*)d_in[20];

  float* hcP  = (float*)d_ws;                               // 8 MB (2 halves)
  float* xT   = (float*)((char*)d_ws + 8388608);            // 4 MB
  float* WqT  = (float*)((char*)d_ws + 12582912);
  float* WkT  = WqT + 16384;
  float* Wc1T = WkT + 16384;
  float* WsT  = Wc1T + 16384;

  xpose<<<256, 256, 0, stream>>>(x, xT);
  prep_t<<<64, 256, 0, stream>>>(Wq, Wk, Wc1, Ws, WqT, WkT, Wc1T, WsT);
  gemm_hcat<<<2048, 256, 0, stream>>>(xT, W1, b1, W2, b2, W3, hcP);
  fused_tail<<<1024, 256, 0, stream>>>(hcP, b3, WqT, bq, WkT, bk, WsT, bs, Wc1T, bc1,
                                       Wc2, bc2, Wg1, bg1, Wg2, bg2, (float*)d_out);
}